// Round 8
// baseline (495.856 us; speedup 1.0000x reference)
//
#include <hip/hip_runtime.h>
#include <hip/hip_bf16.h>

// Problem constants
#define NNODES 4096
#define NEDGES 32768
#define CH 96
#define EPS 1e-5f
#define INV_SQRT3 0.57735026918962576f
#define ALPHA 0.125f

#define EB 32
#define NBLK (NEDGES / EB)    // 1024

// ws layout: msg [0,393216) fp32, stats [393216,393328),
// bf16 fragment mirrors at float index 393344
#define OFF_MSG 0
#define OFF_ST  393216
#define OFF_WSB 393344
#define WSB_W2_U16 (OFF_WSB * 2)
#define WSB_W1_U16 (WSB_W2_U16 + 524288)
#define WS_BYTES1 (393328 * 4)
#define WS_BYTES2 (393344 * 4 + 524288 * 2 + 16384 * 2)

typedef __attribute__((ext_vector_type(8))) short short8;
typedef __attribute__((ext_vector_type(4))) float floatx4;

__device__ __forceinline__ unsigned short f2bf(float f) {
  union { float f; unsigned int u; } v; v.f = f;
  return (unsigned short)((v.u + 0x7FFFu + ((v.u >> 16) & 1u)) >> 16);
}
__device__ __forceinline__ float fin(float x) {
  return (x == x && fabsf(x) < 1e30f) ? x : 0.f;
}
__device__ __forceinline__ float dlrelu(float g) {
  return (fabsf(g) <= 10.f) ? g : 0.01f * g;
}

// ---------------------------------------------------------------------------
// K0: pack w1/w2 to MFMA B-frag order (bf16) + zero msg/stats.
__global__ __launch_bounds__(256) void k0_prep(const float* w1, const float* w2,
                                               float* ws, int ok1, int ok2) {
  __shared__ float tile[128 * 16];
  const int t = threadIdx.x;
  const int b = blockIdx.x;
  unsigned short* wsu = (unsigned short*)ws;

  if (ok1) {
    for (int i = b * 256 + t; i < 393328; i += 256 * 256) ws[i] = 0.f;
  }
  if (ok2) {
    {
      const int T = b;
#pragma unroll
      for (int p = 0; p < 8; p++) {
        int k = p * 16 + (t >> 4), col = t & 15;
        tile[k * 16 + col] = w2[(size_t)k * 4096 + T * 16 + col];
      }
      __syncthreads();
      int s = t >> 6, lane = t & 63, q = (lane >> 4), cl = lane & 15;
      unsigned int r[4];
#pragma unroll
      for (int jj = 0; jj < 4; jj++) {
        int k0 = s * 32 + q * 8 + 2 * jj;
        unsigned int lo = f2bf(tile[k0 * 16 + cl]);
        unsigned int hi = f2bf(tile[(k0 + 1) * 16 + cl]);
        r[jj] = lo | (hi << 16);
      }
      *(uint4*)(wsu + WSB_W2_U16 + ((size_t)(T * 4 + s) * 64 + lane) * 8) =
          make_uint4(r[0], r[1], r[2], r[3]);
    }
    if (b < 8) {
      __syncthreads();
      const int T = b;
#pragma unroll
      for (int p = 0; p < 8; p++) {
        int k = p * 16 + (t >> 4), col = t & 15;
        tile[k * 16 + col] = w1[(size_t)k * 128 + T * 16 + col];
      }
      __syncthreads();
      int s = t >> 6, lane = t & 63, q = (lane >> 4), cl = lane & 15;
      unsigned int r[4];
#pragma unroll
      for (int jj = 0; jj < 4; jj++) {
        int k0 = s * 32 + q * 8 + 2 * jj;
        unsigned int lo = f2bf(tile[k0 * 16 + cl]);
        unsigned int hi = f2bf(tile[(k0 + 1) * 16 + cl]);
        r[jj] = lo | (hi << 16);
      }
      *(uint4*)(wsu + WSB_W1_U16 + ((size_t)(T * 4 + s) * 64 + lane) * 8) =
          make_uint4(r[0], r[1], r[2], r[3]);
    }
  }
}

// ---------------------------------------------------------------------------
// K1: fused edge pipeline. 32 edges/block, 512 thr (8 waves), 1024 blocks,
// 4 blk/CU = 32 waves/CU. Rotating register B+bias prefetch; LDS overlay.
__global__ __launch_bounds__(512, 8) void k1_fused(const int* eidx, const float* na,
                                                   const float* ea, const float* esh,
                                                   const float* b1g, const float* b2g,
                                                   float* ws, int ok2) {
  if (!ok2) return;
  __shared__ float a_lds[EB * 161];                 // 20608 B
  __shared__ __align__(16) char ovl[EB * 113 * 4];  // 14464 B: hscr then acc_lds
  __shared__ float ss_lds[EB];
  __shared__ float sv_lds[EB][3];
  __shared__ int dst_lds[EB];
  __shared__ int src_lds[EB];
  unsigned short* hscr = (unsigned short*)ovl;      // [e][k] stride 136, bf16
  float* acc_lds = (float*)ovl;                     // [e][oi] stride 113

  const int tid = threadIdx.x;
  const int lane = tid & 63;
  const int q = lane >> 4;
  const int cl = lane & 15;
  const int wv = tid >> 6;      // 0..7
  const int e0 = blockIdx.x * EB;
  unsigned short* wsu = (unsigned short*)ws;
  float* msg = ws;

  // ---- phase 0: edge meta + int64/int32 detection
  if (tid < EB) {
    int o = 0;
    for (int i = 1; i < 256; i += 2) o |= eidx[i];
    const int is64 = (o == 0);
    int e = e0 + tid;
    int s = is64 ? eidx[2 * e] : eidx[e];
    int d = is64 ? eidx[2 * (NEDGES + e)] : eidx[NEDGES + e];
    src_lds[tid] = s & (NNODES - 1);
    dst_lds[tid] = d & (NNODES - 1);
    float4 sh = *(const float4*)(esh + (size_t)e * 4);
    ss_lds[tid] = sh.x;
    sv_lds[tid][0] = sh.y; sv_lds[tid][1] = sh.z; sv_lds[tid][2] = sh.w;
  }
  __syncthreads();

  // ---- phase 1b: gather per-edge activations
  for (int idx = tid; idx < EB * 160; idx += 512) {
    int e = idx / 160, i = idx - e * 160;
    const float* x = na + (size_t)src_lds[e] * CH;
    float v;
    if (i < 48) v = x[i] * ss_lds[e];
    else if (i < 64) {
      int ii = i - 48;
      v = (x[48 + 3 * ii] * sv_lds[e][0] + x[49 + 3 * ii] * sv_lds[e][1] +
           x[50 + 3 * ii] * sv_lds[e][2]) * INV_SQRT3;
    } else if (i < 112) v = x[i - 64];
    else v = x[48 + (i - 112)];
    a_lds[e * 161 + i] = v;
  }

  // ---- phase 1c: GEMM1  h = relu(ea@w1+b1) -> hscr (one 16-col tile/wave)
  {
    short8 a1[2][4];
#pragma unroll
    for (int mt = 0; mt < 2; mt++)
#pragma unroll
      for (int ks = 0; ks < 4; ks++) {
        const float* src = ea + (size_t)(e0 + mt * 16 + cl) * 128 + ks * 32 + q * 8;
        float4 v0 = *(const float4*)src;
        float4 v1 = *(const float4*)(src + 4);
        union { short8 s; unsigned int u[4]; } pk;
        pk.u[0] = f2bf(v0.x) | ((unsigned)f2bf(v0.y) << 16);
        pk.u[1] = f2bf(v0.z) | ((unsigned)f2bf(v0.w) << 16);
        pk.u[2] = f2bf(v1.x) | ((unsigned)f2bf(v1.y) << 16);
        pk.u[3] = f2bf(v1.z) | ((unsigned)f2bf(v1.w) << 16);
        a1[mt][ks] = pk.s;
      }
    const short8* w1f = (const short8*)(wsu + WSB_W1_U16);
    const int nt = wv;
    int hcol = nt * 16 + cl;
    float hb = b1g[hcol];
    floatx4 c0 = (floatx4)(hb), c1 = (floatx4)(hb);
#pragma unroll
    for (int ks = 0; ks < 4; ks++) {
      short8 bf = w1f[(nt * 4 + ks) * 64 + lane];
      c0 = __builtin_amdgcn_mfma_f32_16x16x32_bf16(a1[0][ks], bf, c0, 0, 0, 0);
      c1 = __builtin_amdgcn_mfma_f32_16x16x32_bf16(a1[1][ks], bf, c1, 0, 0, 0);
    }
#pragma unroll
    for (int r = 0; r < 4; r++) {
      hscr[(q * 4 + r) * 136 + hcol] = f2bf(fmaxf(c0[r], 0.f));
      hscr[(16 + q * 4 + r) * 136 + hcol] = f2bf(fmaxf(c1[r], 0.f));
    }
  }
  __syncthreads();

  // ---- phase 2: A fragments (h) -> registers
  short8 areg[2][4];
#pragma unroll
  for (int mt = 0; mt < 2; mt++)
#pragma unroll
    for (int ks = 0; ks < 4; ks++)
      areg[mt][ks] = *(const short8*)&hscr[(mt * 16 + cl) * 136 + ks * 32 + q * 8];
  __syncthreads();   // all hscr reads done; ovl can be reused

  // zero acc_lds (overlay)
  for (int idx = tid; idx < EB * 113; idx += 512) acc_lds[idx] = 0.f;
  __syncthreads();

  // ---- phase 3: main loop, per-wave tile ranges, register B+bias prefetch
  const short8* w2f = (const short8*)(wsu + WSB_W2_U16);

#define LOADB(dst, bdst, uu) { const short8* _p = w2f + (size_t)((uu)&255) * 256 + lane; \
    dst[0] = _p[0]; dst[1] = _p[64]; dst[2] = _p[128]; dst[3] = _p[192]; \
    bdst = b2g[((uu)&255) * 16 + cl]; }

#define MFMA8(bb, bsc, c0, c1) \
    floatx4 c0 = (floatx4)(bsc), c1 = (floatx4)(bsc); \
    _Pragma("unroll") \
    for (int ks = 0; ks < 4; ks++) { \
      c0 = __builtin_amdgcn_mfma_f32_16x16x32_bf16(areg[0][ks], bb[ks], c0, 0, 0, 0); \
      c1 = __builtin_amdgcn_mfma_f32_16x16x32_bf16(areg[1][ks], bb[ks], c1, 0, 0, 0); }

  if (wv < 6) {
    // ss/vs class: ai-groups starts {0,11,22,33,44,54}, counts {11,11,11,11,10,10}
    const int g0 = wv * 11 - ((wv > 4) ? (wv - 4) : 0);
    const int ng = (wv < 4) ? 11 : 10;
    const int u0 = g0 * 3;
    float accS[3][2][4];
#pragma unroll
    for (int c = 0; c < 3; c++)
#pragma unroll
      for (int mt = 0; mt < 2; mt++)
#pragma unroll
        for (int r = 0; r < 4; r++) accS[c][mt][r] = 0.f;

    short8 b0[4], b1[4], b2[4];
    float bb0, bb1, bb2;
    LOADB(b0, bb0, u0); LOADB(b1, bb1, u0 + 1);
    for (int g = 0; g < ng; g++) {
      const int ai = g0 + g;
      const int u = u0 + 3 * g;
      float av[2][4];
#pragma unroll
      for (int mt = 0; mt < 2; mt++)
#pragma unroll
        for (int r = 0; r < 4; r++)
          av[mt][r] = a_lds[(mt * 16 + q * 4 + r) * 161 + ai];

#define COMP_SS(bb, bsc, cidx) { \
      MFMA8(bb, bsc, c0, c1); \
      _Pragma("unroll") \
      for (int r = 0; r < 4; r++) { \
        accS[cidx][0][r] += av[0][r] * dlrelu(c0[r]); \
        accS[cidx][1][r] += av[1][r] * dlrelu(c1[r]); } }

      LOADB(b2, bb2, u + 2); COMP_SS(b0, bb0, 0);
      LOADB(b0, bb0, u + 3); COMP_SS(b1, bb1, 1);
      LOADB(b1, bb1, u + 4); COMP_SS(b2, bb2, 2);
    }
    // phase 4 (ss): lane owns (e, c*16+cl)
#pragma unroll
    for (int mt = 0; mt < 2; mt++)
#pragma unroll
      for (int r = 0; r < 4; r++) {
        int e = mt * 16 + q * 4 + r;
#pragma unroll
        for (int c = 0; c < 3; c++)
          atomicAdd(&acc_lds[e * 113 + c * 16 + cl], accS[c][mt][r]);
      }
  } else {
    // wave 6: sv u[192,224); wave 7: sv u[224,240) + vv u[240,256)
    float accT[2][4], accV[2][4][3];
#pragma unroll
    for (int mt = 0; mt < 2; mt++)
#pragma unroll
      for (int r = 0; r < 4; r++) {
        accT[mt][r] = 0.f;
        accV[mt][r][0] = 0.f; accV[mt][r][1] = 0.f; accV[mt][r][2] = 0.f;
      }
    short8 b0[4], b1[4];
    float bb0, bb1;

#define COMP_SV(bb, bsc, uu) { \
    const int ai = (uu) - 128; \
    MFMA8(bb, bsc, c0, c1); \
    _Pragma("unroll") \
    for (int r = 0; r < 4; r++) { \
      accT[0][r] += a_lds[(q * 4 + r) * 161 + ai] * dlrelu(c0[r]); \
      accT[1][r] += a_lds[(16 + q * 4 + r) * 161 + ai] * dlrelu(c1[r]); } }

#define COMP_VV(bb, bsc, uu) { \
    const int ab = 3 * (uu) - 608; \
    MFMA8(bb, bsc, c0, c1); \
    _Pragma("unroll") \
    for (int r = 0; r < 4; r++) { \
      float w0 = dlrelu(c0[r]), w1v = dlrelu(c1[r]); \
      int ba0 = (q * 4 + r) * 161 + ab, ba1 = (16 + q * 4 + r) * 161 + ab; \
      accV[0][r][0] += a_lds[ba0 + 0] * w0; \
      accV[0][r][1] += a_lds[ba0 + 1] * w0; \
      accV[0][r][2] += a_lds[ba0 + 2] * w0; \
      accV[1][r][0] += a_lds[ba1 + 0] * w1v; \
      accV[1][r][1] += a_lds[ba1 + 1] * w1v; \
      accV[1][r][2] += a_lds[ba1 + 2] * w1v; } }

    if (wv == 6) {
      LOADB(b0, bb0, 192);
      for (int i = 0; i < 32; i += 2) {
        const int u = 192 + i;
        LOADB(b1, bb1, u + 1); COMP_SV(b0, bb0, u);
        LOADB(b0, bb0, u + 2); COMP_SV(b1, bb1, u + 1);
      }
    } else {
      LOADB(b0, bb0, 224);
      for (int i = 0; i < 16; i += 2) {
        const int u = 224 + i;
        LOADB(b1, bb1, u + 1); COMP_SV(b0, bb0, u);
        LOADB(b0, bb0, u + 2); COMP_SV(b1, bb1, u + 1);
      }
      for (int i = 0; i < 16; i += 2) {
        const int u = 240 + i;
        LOADB(b1, bb1, u + 1); COMP_VV(b0, bb0, u);
        LOADB(b0, bb0, u + 2); COMP_VV(b1, bb1, u + 1);
      }
    }
    // phase 4 (sv/vv): lane owns (e,48+cl) and (e,64+3cl+m)
#pragma unroll
    for (int mt = 0; mt < 2; mt++)
#pragma unroll
      for (int r = 0; r < 4; r++) {
        int e = mt * 16 + q * 4 + r;
        atomicAdd(&acc_lds[e * 113 + 48 + cl], accT[mt][r]);
        if (wv == 7) {
#pragma unroll
          for (int m = 0; m < 3; m++)
            atomicAdd(&acc_lds[e * 113 + 64 + 3 * cl + m], accV[mt][r][m]);
        }
      }
  }
  __syncthreads();

  // ---- phase 5: build 96-ch message, scatter to node accumulator
  for (int idx = tid; idx < EB * 96; idx += 512) {
    int e = idx / 96, c = idx - e * 96;
    float val;
    if (c < 48) val = ALPHA * acc_lds[e * 113 + c];
    else {
      int t2 = c - 48; int k = t2 / 3; int m = t2 - k * 3;
      val = ALPHA * (acc_lds[e * 113 + 48 + k] * sv_lds[e][m] +
                     ss_lds[e] * acc_lds[e * 113 + 64 + 3 * k + m]);
    }
    atomicAdd(msg + (size_t)dst_lds[e] * CH + c, val);
  }
}

// ---------------------------------------------------------------------------
__global__ __launch_bounds__(256) void k2_stats(const float* na, float* ws, int ok1) {
  __shared__ float part[112];
  const float* msg = ws + OFF_MSG;
  float* st = ws + OFF_ST;
  for (int i = threadIdx.x; i < 112; i += 256) part[i] = 0.f;
  __syncthreads();
  if (ok1) {
    int stride = gridDim.x * 256;
    for (int idx = blockIdx.x * 256 + threadIdx.x; idx < NNODES * CH; idx += stride) {
      int c = idx % CH;
      float t = msg[idx] + na[idx];
      if (c < 48) { atomicAdd(&part[c], t); atomicAdd(&part[48 + c], t * t); }
      else { int k = (c - 48) / 3; atomicAdd(&part[96 + k], t * t); }
    }
    __syncthreads();
    for (int i = threadIdx.x; i < 112; i += 256) atomicAdd(&st[i], part[i]);
  }
}

// ---------------------------------------------------------------------------
__global__ __launch_bounds__(256) void k3_final(const float* na, const float* bnw,
                                                const float* bnb, const float* ws,
                                                float* out, int ok1) {
  __shared__ float mean_s[48], scale_s[48], bias_s[48], scale_v[16];
  const float* msg = ws + OFF_MSG;
  const float* st = ws + OFF_ST;
  const int tid = threadIdx.x;
  if (tid < 48) {
    float s1 = ok1 ? fin(st[tid]) : 0.f;
    float s2 = ok1 ? fin(st[48 + tid]) : 0.f;
    float m = s1 * (1.f / NNODES);
    float var = fmaxf(s2 * (1.f / NNODES) - m * m, 0.f);
    mean_s[tid] = m;
    scale_s[tid] = rsqrtf(var + EPS) * bnw[tid];
    bias_s[tid] = bnb[tid];
  } else if (tid < 64) {
    int k = tid - 48;
    float s2 = ok1 ? fin(st[96 + k]) : 0.f;
    scale_v[k] = rsqrtf(fmaxf(s2 * (1.f / (3.f * NNODES)), 0.f) + EPS) * bnw[48 + k];
  }
  __syncthreads();
  int stride = gridDim.x * 256;
  for (int idx = blockIdx.x * 256 + tid; idx < NNODES * CH; idx += stride) {
    int c = idx % CH;
    float t = (ok1 ? msg[idx] : 0.f) + na[idx];
    float o;
    if (c < 48) o = (t - mean_s[c]) * scale_s[c] + bias_s[c];
    else { int k = (c - 48) / 3; o = t * scale_v[k]; }
    out[idx] = fin(o);
  }
}

// ---------------------------------------------------------------------------
extern "C" void kernel_launch(void* const* d_in, const int* in_sizes, int n_in,
                              void* d_out, int out_size, void* d_ws, size_t ws_size,
                              hipStream_t stream) {
  const float* na  = (const float*)d_in[0];
  const int* eidx  = (const int*)d_in[1];
  const float* ea  = (const float*)d_in[2];
  const float* esh = (const float*)d_in[3];
  const float* w1  = (const float*)d_in[4];
  const float* b1  = (const float*)d_in[5];
  const float* w2  = (const float*)d_in[6];
  const float* b2  = (const float*)d_in[7];
  const float* bnw = (const float*)d_in[8];
  const float* bnb = (const float*)d_in[9];
  float* out = (float*)d_out;
  float* ws = (float*)d_ws;
  const int ok1 = (ws_size >= (size_t)WS_BYTES1) ? 1 : 0;
  const int ok2 = (ws_size >= (size_t)WS_BYTES2) ? 1 : 0;

  hipLaunchKernelGGL(k0_prep,  dim3(256), dim3(256), 0, stream, w1, w2, ws, ok1, ok2);
  hipLaunchKernelGGL(k1_fused, dim3(NBLK), dim3(512), 0, stream,
                     eidx, na, ea, esh, b1, b2, ws, ok2);
  hipLaunchKernelGGL(k2_stats, dim3(512), dim3(256), 0, stream, na, ws, ok1);
  hipLaunchKernelGGL(k3_final, dim3(512), dim3(256), 0, stream, na, bnw, bnb, ws, out, ok1);
}

// Round 9
// 437.164 us; speedup vs baseline: 1.1343x; 1.1343x over previous
//
#include <hip/hip_runtime.h>
#include <hip/hip_bf16.h>

// Problem constants
#define NNODES 4096
#define NEDGES 32768
#define CH 96
#define EPS 1e-5f
#define INV_SQRT3 0.57735026918962576f
#define ALPHA 0.125f

#define EB 32
#define NBLK (NEDGES / EB)    // 1024

// ws layout: msg [0,393216) fp32, stats [393216,393328), barrier ctr [393328],
// bf16 fragment mirrors at float index 393344
#define OFF_MSG 0
#define OFF_ST  393216
#define OFF_WSB 393344
#define WSB_W2_U16 (OFF_WSB * 2)
#define WSB_W1_U16 (WSB_W2_U16 + 524288)
#define WS_BYTES1 (393330 * 4)
#define WS_BYTES2 (393344 * 4 + 524288 * 2 + 16384 * 2)

typedef __attribute__((ext_vector_type(8))) short short8;
typedef __attribute__((ext_vector_type(4))) float floatx4;

__device__ __forceinline__ unsigned short f2bf(float f) {
  union { float f; unsigned int u; } v; v.f = f;
  return (unsigned short)((v.u + 0x7FFFu + ((v.u >> 16) & 1u)) >> 16);
}
__device__ __forceinline__ float bf2f(unsigned short u) {
  union { unsigned int i; float f; } v; v.i = ((unsigned int)u) << 16; return v.f;
}
__device__ __forceinline__ float fin(float x) {
  return (x == x && fabsf(x) < 1e30f) ? x : 0.f;
}
__device__ __forceinline__ float dlrelu(float g) {
  return (fabsf(g) <= 10.f) ? g : 0.01f * g;
}

// ---------------------------------------------------------------------------
// K0: pack w1/w2 to MFMA B-frag order (bf16) + zero msg/stats/ctr.
__global__ __launch_bounds__(256) void k0_prep(const float* w1, const float* w2,
                                               float* ws, int ok1, int ok2) {
  __shared__ float tile[128 * 16];
  const int t = threadIdx.x;
  const int b = blockIdx.x;
  unsigned short* wsu = (unsigned short*)ws;

  if (ok1) {
    for (int i = b * 256 + t; i < 393330; i += 256 * 256) ws[i] = 0.f;
  }
  if (ok2) {
    {
      const int T = b;
#pragma unroll
      for (int p = 0; p < 8; p++) {
        int k = p * 16 + (t >> 4), col = t & 15;
        tile[k * 16 + col] = w2[(size_t)k * 4096 + T * 16 + col];
      }
      __syncthreads();
      int s = t >> 6, lane = t & 63, q = (lane >> 4), cl = lane & 15;
      unsigned int r[4];
#pragma unroll
      for (int jj = 0; jj < 4; jj++) {
        int k0 = s * 32 + q * 8 + 2 * jj;
        unsigned int lo = f2bf(tile[k0 * 16 + cl]);
        unsigned int hi = f2bf(tile[(k0 + 1) * 16 + cl]);
        r[jj] = lo | (hi << 16);
      }
      *(uint4*)(wsu + WSB_W2_U16 + ((size_t)(T * 4 + s) * 64 + lane) * 8) =
          make_uint4(r[0], r[1], r[2], r[3]);
    }
    if (b < 8) {
      __syncthreads();
      const int T = b;
#pragma unroll
      for (int p = 0; p < 8; p++) {
        int k = p * 16 + (t >> 4), col = t & 15;
        tile[k * 16 + col] = w1[(size_t)k * 128 + T * 16 + col];
      }
      __syncthreads();
      int s = t >> 6, lane = t & 63, q = (lane >> 4), cl = lane & 15;
      unsigned int r[4];
#pragma unroll
      for (int jj = 0; jj < 4; jj++) {
        int k0 = s * 32 + q * 8 + 2 * jj;
        unsigned int lo = f2bf(tile[k0 * 16 + cl]);
        unsigned int hi = f2bf(tile[(k0 + 1) * 16 + cl]);
        r[jj] = lo | (hi << 16);
      }
      *(uint4*)(wsu + WSB_W1_U16 + ((size_t)(T * 4 + s) * 64 + lane) * 8) =
          make_uint4(r[0], r[1], r[2], r[3]);
    }
  }
}

// ---------------------------------------------------------------------------
// K1: fused edge pipeline. 32 edges/block, 256 thr (4 waves), 1024 blocks.
// LDS 19.8 KB -> 8 blocks/CU; VGPR capped 64 -> 32 waves/CU.
__global__ __launch_bounds__(256, 8) void k1_fused(const int* eidx, const float* na,
                                                   const float* ea, const float* esh,
                                                   const float* b1g, const float* b2g,
                                                   float* ws, int ok2) {
  if (!ok2) return;
  __shared__ __align__(16) unsigned short a_lds[EB * 161];  // bf16 activations, 10304 B
  __shared__ __align__(16) char ovl[8704];                  // hscr, then tmp|vv
  __shared__ float ss_lds[EB];
  __shared__ float sv_lds[EB][3];
  __shared__ int dst_lds[EB];
  __shared__ int src_lds[EB];
  unsigned short* hscr = (unsigned short*)ovl;   // [e][k] stride 136, bf16
  float* tmp_l = (float*)ovl;                    // [e][17] fp32
  float* vv_l  = (float*)(ovl + 2176);           // [e][49] fp32

  const int tid = threadIdx.x;
  const int lane = tid & 63;
  const int q = lane >> 4;
  const int cl = lane & 15;
  const int wv = tid >> 6;      // 0..3
  const int e0 = blockIdx.x * EB;
  unsigned short* wsu = (unsigned short*)ws;
  float* msg = ws;

  // ---- phase 0: edge meta + int64/int32 detection
  if (tid < EB) {
    int o = 0;
    for (int i = 1; i < 256; i += 2) o |= eidx[i];
    const int is64 = (o == 0);
    int e = e0 + tid;
    int s = is64 ? eidx[2 * e] : eidx[e];
    int d = is64 ? eidx[2 * (NEDGES + e)] : eidx[NEDGES + e];
    src_lds[tid] = s & (NNODES - 1);
    dst_lds[tid] = d & (NNODES - 1);
    float4 sh = *(const float4*)(esh + (size_t)e * 4);
    ss_lds[tid] = sh.x;
    sv_lds[tid][0] = sh.y; sv_lds[tid][1] = sh.z; sv_lds[tid][2] = sh.w;
  }
  __syncthreads();

  // ---- phase 1b: gather per-edge activations (stored bf16)
  for (int idx = tid; idx < EB * 160; idx += 256) {
    int e = idx / 160, i = idx - e * 160;
    const float* x = na + (size_t)src_lds[e] * CH;
    float v;
    if (i < 48) v = x[i] * ss_lds[e];
    else if (i < 64) {
      int ii = i - 48;
      v = (x[48 + 3 * ii] * sv_lds[e][0] + x[49 + 3 * ii] * sv_lds[e][1] +
           x[50 + 3 * ii] * sv_lds[e][2]) * INV_SQRT3;
    } else if (i < 112) v = x[i - 64];
    else v = x[48 + (i - 112)];
    a_lds[e * 161 + i] = f2bf(v);
  }

  // ---- phase 1c: GEMM1  h = relu(ea@w1+b1) -> hscr (2 tiles/wave)
  {
    short8 a1[2][4];
#pragma unroll
    for (int mt = 0; mt < 2; mt++)
#pragma unroll
      for (int ks = 0; ks < 4; ks++) {
        const float* src = ea + (size_t)(e0 + mt * 16 + cl) * 128 + ks * 32 + q * 8;
        float4 v0 = *(const float4*)src;
        float4 v1 = *(const float4*)(src + 4);
        union { short8 s; unsigned int u[4]; } pk;
        pk.u[0] = f2bf(v0.x) | ((unsigned)f2bf(v0.y) << 16);
        pk.u[1] = f2bf(v0.z) | ((unsigned)f2bf(v0.w) << 16);
        pk.u[2] = f2bf(v1.x) | ((unsigned)f2bf(v1.y) << 16);
        pk.u[3] = f2bf(v1.z) | ((unsigned)f2bf(v1.w) << 16);
        a1[mt][ks] = pk.s;
      }
    const short8* w1f = (const short8*)(wsu + WSB_W1_U16);
#pragma unroll
    for (int t = 0; t < 2; t++) {
      int nt = wv * 2 + t;
      int hcol = nt * 16 + cl;
      float hb = b1g[hcol];
      floatx4 c0 = (floatx4)(hb), c1 = (floatx4)(hb);
#pragma unroll
      for (int ks = 0; ks < 4; ks++) {
        short8 bf = w1f[(nt * 4 + ks) * 64 + lane];
        c0 = __builtin_amdgcn_mfma_f32_16x16x32_bf16(a1[0][ks], bf, c0, 0, 0, 0);
        c1 = __builtin_amdgcn_mfma_f32_16x16x32_bf16(a1[1][ks], bf, c1, 0, 0, 0);
      }
#pragma unroll
      for (int r = 0; r < 4; r++) {
        hscr[(q * 4 + r) * 136 + hcol] = f2bf(fmaxf(c0[r], 0.f));
        hscr[(16 + q * 4 + r) * 136 + hcol] = f2bf(fmaxf(c1[r], 0.f));
      }
    }
  }
  __syncthreads();

  // ---- phase 2: A fragments (h) -> registers
  short8 areg[2][4];
#pragma unroll
  for (int mt = 0; mt < 2; mt++)
#pragma unroll
    for (int ks = 0; ks < 4; ks++)
      areg[mt][ks] = *(const short8*)&hscr[(mt * 16 + cl) * 136 + ks * 32 + q * 8];
  __syncthreads();   // hscr reads done; ovl reusable as tmp/vv

  // ---- phase 3: main loop, per-wave tile ranges, register B+bias prefetch
  const short8* w2f = (const short8*)(wsu + WSB_W2_U16);

#define LOADB(dst, bdst, uu) { const short8* _p = w2f + (size_t)((uu)&255) * 256 + lane; \
    dst[0] = _p[0]; dst[1] = _p[64]; dst[2] = _p[128]; dst[3] = _p[192]; \
    bdst = b2g[((uu)&255) * 16 + cl]; }

#define MFMA8(bb, bsc, c0, c1) \
    floatx4 c0 = (floatx4)(bsc), c1 = (floatx4)(bsc); \
    _Pragma("unroll") \
    for (int ks = 0; ks < 4; ks++) { \
      c0 = __builtin_amdgcn_mfma_f32_16x16x32_bf16(areg[0][ks], bb[ks], c0, 0, 0, 0); \
      c1 = __builtin_amdgcn_mfma_f32_16x16x32_bf16(areg[1][ks], bb[ks], c1, 0, 0, 0); }

  if (wv < 3) {
    // ss/vs class: u in [0,192); wave ranges [0,63),[63,126),[126,192)
    const int ng = (wv == 2) ? 22 : 21;
    const int base_ai = wv * 21;
    const int u0 = base_ai * 3;
    float accS[3][2][4];
#pragma unroll
    for (int c = 0; c < 3; c++)
#pragma unroll
      for (int mt = 0; mt < 2; mt++)
#pragma unroll
        for (int r = 0; r < 4; r++) accS[c][mt][r] = 0.f;

    short8 b0[4], b1[4], b2[4];
    float bb0, bb1, bb2;
    LOADB(b0, bb0, u0); LOADB(b1, bb1, u0 + 1);
    for (int g = 0; g < ng; g++) {
      const int ai = base_ai + g;
      const int u = u0 + 3 * g;
      float av[2][4];
#pragma unroll
      for (int mt = 0; mt < 2; mt++)
#pragma unroll
        for (int r = 0; r < 4; r++)
          av[mt][r] = bf2f(a_lds[(mt * 16 + q * 4 + r) * 161 + ai]);

#define COMP_SS(bb, bsc, cidx) { \
      MFMA8(bb, bsc, c0, c1); \
      _Pragma("unroll") \
      for (int r = 0; r < 4; r++) { \
        accS[cidx][0][r] += av[0][r] * dlrelu(c0[r]); \
        accS[cidx][1][r] += av[1][r] * dlrelu(c1[r]); } }

      LOADB(b2, bb2, u + 2); COMP_SS(b0, bb0, 0);
      LOADB(b0, bb0, u + 3); COMP_SS(b1, bb1, 1);
      LOADB(b1, bb1, u + 4); COMP_SS(b2, bb2, 2);
    }
    // phase 4 (ss): direct global scatter, lane owns (e, c*16+cl)
#pragma unroll
    for (int mt = 0; mt < 2; mt++)
#pragma unroll
      for (int r = 0; r < 4; r++) {
        int e = mt * 16 + q * 4 + r;
        float* mrow = msg + (size_t)dst_lds[e] * CH;
#pragma unroll
        for (int c = 0; c < 3; c++)
          atomicAdd(mrow + c * 16 + cl, ALPHA * accS[c][mt][r]);
      }
  } else {
    // wave 3: sv u[192,240) + vv u[240,256)
    float accT[2][4], accV[2][4][3];
#pragma unroll
    for (int mt = 0; mt < 2; mt++)
#pragma unroll
      for (int r = 0; r < 4; r++) {
        accT[mt][r] = 0.f;
        accV[mt][r][0] = 0.f; accV[mt][r][1] = 0.f; accV[mt][r][2] = 0.f;
      }
    short8 b0[4], b1[4];
    float bb0, bb1;

#define COMP_SV(bb, bsc, uu) { \
    const int ai = (uu) - 128; \
    MFMA8(bb, bsc, c0, c1); \
    _Pragma("unroll") \
    for (int r = 0; r < 4; r++) { \
      accT[0][r] += bf2f(a_lds[(q * 4 + r) * 161 + ai]) * dlrelu(c0[r]); \
      accT[1][r] += bf2f(a_lds[(16 + q * 4 + r) * 161 + ai]) * dlrelu(c1[r]); } }

#define COMP_VV(bb, bsc, uu) { \
    const int ab = 3 * (uu) - 608; \
    MFMA8(bb, bsc, c0, c1); \
    _Pragma("unroll") \
    for (int r = 0; r < 4; r++) { \
      float w0 = dlrelu(c0[r]), w1v = dlrelu(c1[r]); \
      int ba0 = (q * 4 + r) * 161 + ab, ba1 = (16 + q * 4 + r) * 161 + ab; \
      accV[0][r][0] += bf2f(a_lds[ba0 + 0]) * w0; \
      accV[0][r][1] += bf2f(a_lds[ba0 + 1]) * w0; \
      accV[0][r][2] += bf2f(a_lds[ba0 + 2]) * w0; \
      accV[1][r][0] += bf2f(a_lds[ba1 + 0]) * w1v; \
      accV[1][r][1] += bf2f(a_lds[ba1 + 1]) * w1v; \
      accV[1][r][2] += bf2f(a_lds[ba1 + 2]) * w1v; } }

    LOADB(b0, bb0, 192);
    for (int i = 0; i < 48; i += 2) {
      const int u = 192 + i;
      LOADB(b1, bb1, u + 1); COMP_SV(b0, bb0, u);
      LOADB(b0, bb0, u + 2); COMP_SV(b1, bb1, u + 1);
    }
    for (int i = 0; i < 16; i += 2) {
      const int u = 240 + i;
      LOADB(b1, bb1, u + 1); COMP_VV(b0, bb0, u);
      LOADB(b0, bb0, u + 2); COMP_VV(b1, bb1, u + 1);
    }
    // phase 4 (sv/vv): single wave -> plain LDS stores, no atomics
#pragma unroll
    for (int mt = 0; mt < 2; mt++)
#pragma unroll
      for (int r = 0; r < 4; r++) {
        int e = mt * 16 + q * 4 + r;
        tmp_l[e * 17 + cl] = accT[mt][r];
#pragma unroll
        for (int m = 0; m < 3; m++)
          vv_l[e * 49 + 3 * cl + m] = accV[mt][r][m];
      }
  }
  __syncthreads();

  // ---- phase 5: v-channels only (s already scattered)
  for (int idx = tid; idx < EB * 48; idx += 256) {
    int e = idx / 48, t2 = idx - e * 48;
    int k = t2 / 3, m = t2 - k * 3;
    float val = ALPHA * (tmp_l[e * 17 + k] * sv_lds[e][m] +
                         ss_lds[e] * vv_l[e * 49 + 3 * k + m]);
    atomicAdd(msg + (size_t)dst_lds[e] * CH + 48 + t2, val);
  }
}

// ---------------------------------------------------------------------------
// K23: BN stats + device-barrier + normalize, single kernel (512 blocks).
__global__ __launch_bounds__(256) void k23_fused(const float* na, const float* bnw,
                                                 const float* bnb, float* ws,
                                                 float* out, int ok1) {
  __shared__ float part[112];
  __shared__ float mean_s[48], scale_s[48], bias_s[48], scale_v[16];
  float* msg = ws + OFF_MSG;
  float* st = ws + OFF_ST;
  const int tid = threadIdx.x;
  const int stride = gridDim.x * 256;

  if (ok1) {
    for (int i = tid; i < 112; i += 256) part[i] = 0.f;
    __syncthreads();
    for (int idx = blockIdx.x * 256 + tid; idx < NNODES * CH; idx += stride) {
      int c = idx % CH;
      float t = msg[idx] + na[idx];
      if (c < 48) { atomicAdd(&part[c], t); atomicAdd(&part[48 + c], t * t); }
      else { int k = (c - 48) / 3; atomicAdd(&part[96 + k], t * t); }
    }
    __syncthreads();
    for (int i = tid; i < 112; i += 256) atomicAdd(&st[i], part[i]);
    // device-scope barrier (monotonic ctr: replay-safe)
    __syncthreads();
    if (tid == 0) {
      __threadfence();
      int* ctr = (int*)(st + 112);
      atomicAdd(ctr, 1);
      while (__hip_atomic_load(ctr, __ATOMIC_ACQUIRE, __HIP_MEMORY_SCOPE_AGENT) <
             (int)gridDim.x) {}
    }
    __syncthreads();
  }

  if (tid < 48) {
    float s1 = ok1 ? fin(__hip_atomic_load(&st[tid], __ATOMIC_RELAXED,
                                           __HIP_MEMORY_SCOPE_AGENT)) : 0.f;
    float s2 = ok1 ? fin(__hip_atomic_load(&st[48 + tid], __ATOMIC_RELAXED,
                                           __HIP_MEMORY_SCOPE_AGENT)) : 0.f;
    float m = s1 * (1.f / NNODES);
    float var = fmaxf(s2 * (1.f / NNODES) - m * m, 0.f);
    mean_s[tid] = m;
    scale_s[tid] = rsqrtf(var + EPS) * bnw[tid];
    bias_s[tid] = bnb[tid];
  } else if (tid < 64) {
    int k = tid - 48;
    float s2 = ok1 ? fin(__hip_atomic_load(&st[96 + k], __ATOMIC_RELAXED,
                                           __HIP_MEMORY_SCOPE_AGENT)) : 0.f;
    scale_v[k] = rsqrtf(fmaxf(s2 * (1.f / (3.f * NNODES)), 0.f) + EPS) * bnw[48 + k];
  }
  __syncthreads();
  for (int idx = blockIdx.x * 256 + tid; idx < NNODES * CH; idx += stride) {
    int c = idx % CH;
    float t = (ok1 ? msg[idx] : 0.f) + na[idx];
    float o;
    if (c < 48) o = (t - mean_s[c]) * scale_s[c] + bias_s[c];
    else { int k = (c - 48) / 3; o = t * scale_v[k]; }
    out[idx] = fin(o);
  }
}

// ---------------------------------------------------------------------------
extern "C" void kernel_launch(void* const* d_in, const int* in_sizes, int n_in,
                              void* d_out, int out_size, void* d_ws, size_t ws_size,
                              hipStream_t stream) {
  const float* na  = (const float*)d_in[0];
  const int* eidx  = (const int*)d_in[1];
  const float* ea  = (const float*)d_in[2];
  const float* esh = (const float*)d_in[3];
  const float* w1  = (const float*)d_in[4];
  const float* b1  = (const float*)d_in[5];
  const float* w2  = (const float*)d_in[6];
  const float* b2  = (const float*)d_in[7];
  const float* bnw = (const float*)d_in[8];
  const float* bnb = (const float*)d_in[9];
  float* out = (float*)d_out;
  float* ws = (float*)d_ws;
  const int ok1 = (ws_size >= (size_t)WS_BYTES1) ? 1 : 0;
  const int ok2 = (ws_size >= (size_t)WS_BYTES2) ? 1 : 0;

  hipLaunchKernelGGL(k0_prep,   dim3(256), dim3(256), 0, stream, w1, w2, ws, ok1, ok2);
  hipLaunchKernelGGL(k1_fused,  dim3(NBLK), dim3(256), 0, stream,
                     eidx, na, ea, esh, b1, b2, ws, ok2);
  hipLaunchKernelGGL(k23_fused, dim3(512), dim3(256), 0, stream,
                     na, bnw, bnb, ws, out, ok1);
}

// Round 10
// 211.045 us; speedup vs baseline: 2.3495x; 2.0714x over previous
//
#include <hip/hip_runtime.h>
#include <hip/hip_bf16.h>

// Problem constants
#define NNODES 4096
#define NEDGES 32768
#define CH 96
#define EPS 1e-5f
#define INV_SQRT3 0.57735026918962576f
#define ALPHA 0.125f

#define EB 32
#define NBLK (NEDGES / EB)    // 1024

// ws layout: msg [0,393216) fp32, stats [393216,393328), barrier ctr [393328],
// bf16 fragment mirrors at float index 393344
#define OFF_MSG 0
#define OFF_ST  393216
#define OFF_WSB 393344
#define WSB_W2_U16 (OFF_WSB * 2)
#define WSB_W1_U16 (WSB_W2_U16 + 524288)
#define WS_BYTES1 (393330 * 4)
#define WS_BYTES2 (393344 * 4 + 524288 * 2 + 16384 * 2)

typedef __attribute__((ext_vector_type(8))) short short8;
typedef __attribute__((ext_vector_type(4))) float floatx4;

__device__ __forceinline__ unsigned short f2bf(float f) {
  union { float f; unsigned int u; } v; v.f = f;
  return (unsigned short)((v.u + 0x7FFFu + ((v.u >> 16) & 1u)) >> 16);
}
__device__ __forceinline__ float bf2f(unsigned short u) {
  union { unsigned int i; float f; } v; v.i = ((unsigned int)u) << 16; return v.f;
}
__device__ __forceinline__ float fin(float x) {
  return (x == x && fabsf(x) < 1e30f) ? x : 0.f;
}
__device__ __forceinline__ float dlrelu(float g) {
  return (fabsf(g) <= 10.f) ? g : 0.01f * g;
}

// ---------------------------------------------------------------------------
// K0: pack w1/w2 to MFMA B-frag order (bf16) + zero msg/stats/ctr.
__global__ __launch_bounds__(256) void k0_prep(const float* w1, const float* w2,
                                               float* ws, int ok1, int ok2) {
  __shared__ float tile[128 * 16];
  const int t = threadIdx.x;
  const int b = blockIdx.x;
  unsigned short* wsu = (unsigned short*)ws;

  if (ok1) {
    for (int i = b * 256 + t; i < 393330; i += 256 * 256) ws[i] = 0.f;
  }
  if (ok2) {
    {
      const int T = b;
#pragma unroll
      for (int p = 0; p < 8; p++) {
        int k = p * 16 + (t >> 4), col = t & 15;
        tile[k * 16 + col] = w2[(size_t)k * 4096 + T * 16 + col];
      }
      __syncthreads();
      int s = t >> 6, lane = t & 63, q = (lane >> 4), cl = lane & 15;
      unsigned int r[4];
#pragma unroll
      for (int jj = 0; jj < 4; jj++) {
        int k0 = s * 32 + q * 8 + 2 * jj;
        unsigned int lo = f2bf(tile[k0 * 16 + cl]);
        unsigned int hi = f2bf(tile[(k0 + 1) * 16 + cl]);
        r[jj] = lo | (hi << 16);
      }
      *(uint4*)(wsu + WSB_W2_U16 + ((size_t)(T * 4 + s) * 64 + lane) * 8) =
          make_uint4(r[0], r[1], r[2], r[3]);
    }
    if (b < 8) {
      __syncthreads();
      const int T = b;
#pragma unroll
      for (int p = 0; p < 8; p++) {
        int k = p * 16 + (t >> 4), col = t & 15;
        tile[k * 16 + col] = w1[(size_t)k * 128 + T * 16 + col];
      }
      __syncthreads();
      int s = t >> 6, lane = t & 63, q = (lane >> 4), cl = lane & 15;
      unsigned int r[4];
#pragma unroll
      for (int jj = 0; jj < 4; jj++) {
        int k0 = s * 32 + q * 8 + 2 * jj;
        unsigned int lo = f2bf(tile[k0 * 16 + cl]);
        unsigned int hi = f2bf(tile[(k0 + 1) * 16 + cl]);
        r[jj] = lo | (hi << 16);
      }
      *(uint4*)(wsu + WSB_W1_U16 + ((size_t)(T * 4 + s) * 64 + lane) * 8) =
          make_uint4(r[0], r[1], r[2], r[3]);
    }
  }
}

// ---------------------------------------------------------------------------
// K1: fused edge pipeline. 32 edges/block, 256 thr (4 waves), 1024 blocks.
// __launch_bounds__(256,4): VGPR budget 128/wave — the proven no-spill config
// (R7: VGPR=64, FETCH 17 MB). N>4 forces a 32-VGPR cap -> catastrophic spills.
__global__ __launch_bounds__(256, 4) void k1_fused(const int* eidx, const float* na,
                                                   const float* ea, const float* esh,
                                                   const float* b1g, const float* b2g,
                                                   float* ws, int ok2) {
  if (!ok2) return;
  __shared__ __align__(16) unsigned short a_lds[EB * 161];  // bf16 activations, 10304 B
  __shared__ __align__(16) char ovl[8704];                  // hscr, then tmp|vv
  __shared__ float ss_lds[EB];
  __shared__ float sv_lds[EB][3];
  __shared__ int dst_lds[EB];
  __shared__ int src_lds[EB];
  unsigned short* hscr = (unsigned short*)ovl;   // [e][k] stride 136, bf16
  float* tmp_l = (float*)ovl;                    // [e][17] fp32
  float* vv_l  = (float*)(ovl + 2176);           // [e][49] fp32

  const int tid = threadIdx.x;
  const int lane = tid & 63;
  const int q = lane >> 4;
  const int cl = lane & 15;
  const int wv = tid >> 6;      // 0..3
  const int e0 = blockIdx.x * EB;
  unsigned short* wsu = (unsigned short*)ws;
  float* msg = ws;

  // ---- phase 0: edge meta + int64/int32 detection
  if (tid < EB) {
    int o = 0;
    for (int i = 1; i < 256; i += 2) o |= eidx[i];
    const int is64 = (o == 0);
    int e = e0 + tid;
    int s = is64 ? eidx[2 * e] : eidx[e];
    int d = is64 ? eidx[2 * (NEDGES + e)] : eidx[NEDGES + e];
    src_lds[tid] = s & (NNODES - 1);
    dst_lds[tid] = d & (NNODES - 1);
    float4 sh = *(const float4*)(esh + (size_t)e * 4);
    ss_lds[tid] = sh.x;
    sv_lds[tid][0] = sh.y; sv_lds[tid][1] = sh.z; sv_lds[tid][2] = sh.w;
  }
  __syncthreads();

  // ---- phase 1b: gather per-edge activations (stored bf16)
  for (int idx = tid; idx < EB * 160; idx += 256) {
    int e = idx / 160, i = idx - e * 160;
    const float* x = na + (size_t)src_lds[e] * CH;
    float v;
    if (i < 48) v = x[i] * ss_lds[e];
    else if (i < 64) {
      int ii = i - 48;
      v = (x[48 + 3 * ii] * sv_lds[e][0] + x[49 + 3 * ii] * sv_lds[e][1] +
           x[50 + 3 * ii] * sv_lds[e][2]) * INV_SQRT3;
    } else if (i < 112) v = x[i - 64];
    else v = x[48 + (i - 112)];
    a_lds[e * 161 + i] = f2bf(v);
  }

  // ---- phase 1c: GEMM1  h = relu(ea@w1+b1) -> hscr (2 tiles/wave)
  {
    short8 a1[2][4];
#pragma unroll
    for (int mt = 0; mt < 2; mt++)
#pragma unroll
      for (int ks = 0; ks < 4; ks++) {
        const float* src = ea + (size_t)(e0 + mt * 16 + cl) * 128 + ks * 32 + q * 8;
        float4 v0 = *(const float4*)src;
        float4 v1 = *(const float4*)(src + 4);
        union { short8 s; unsigned int u[4]; } pk;
        pk.u[0] = f2bf(v0.x) | ((unsigned)f2bf(v0.y) << 16);
        pk.u[1] = f2bf(v0.z) | ((unsigned)f2bf(v0.w) << 16);
        pk.u[2] = f2bf(v1.x) | ((unsigned)f2bf(v1.y) << 16);
        pk.u[3] = f2bf(v1.z) | ((unsigned)f2bf(v1.w) << 16);
        a1[mt][ks] = pk.s;
      }
    const short8* w1f = (const short8*)(wsu + WSB_W1_U16);
#pragma unroll
    for (int t = 0; t < 2; t++) {
      int nt = wv * 2 + t;
      int hcol = nt * 16 + cl;
      float hb = b1g[hcol];
      floatx4 c0 = (floatx4)(hb), c1 = (floatx4)(hb);
#pragma unroll
      for (int ks = 0; ks < 4; ks++) {
        short8 bf = w1f[(nt * 4 + ks) * 64 + lane];
        c0 = __builtin_amdgcn_mfma_f32_16x16x32_bf16(a1[0][ks], bf, c0, 0, 0, 0);
        c1 = __builtin_amdgcn_mfma_f32_16x16x32_bf16(a1[1][ks], bf, c1, 0, 0, 0);
      }
#pragma unroll
      for (int r = 0; r < 4; r++) {
        hscr[(q * 4 + r) * 136 + hcol] = f2bf(fmaxf(c0[r], 0.f));
        hscr[(16 + q * 4 + r) * 136 + hcol] = f2bf(fmaxf(c1[r], 0.f));
      }
    }
  }
  __syncthreads();

  // ---- phase 2: A fragments (h) -> registers
  short8 areg[2][4];
#pragma unroll
  for (int mt = 0; mt < 2; mt++)
#pragma unroll
    for (int ks = 0; ks < 4; ks++)
      areg[mt][ks] = *(const short8*)&hscr[(mt * 16 + cl) * 136 + ks * 32 + q * 8];
  __syncthreads();   // hscr reads done; ovl reusable as tmp/vv

  // ---- phase 3: main loop, per-wave tile ranges, register B+bias prefetch
  const short8* w2f = (const short8*)(wsu + WSB_W2_U16);

#define LOADB(dst, bdst, uu) { const short8* _p = w2f + (size_t)((uu)&255) * 256 + lane; \
    dst[0] = _p[0]; dst[1] = _p[64]; dst[2] = _p[128]; dst[3] = _p[192]; \
    bdst = b2g[((uu)&255) * 16 + cl]; }

#define MFMA8(bb, bsc, c0, c1) \
    floatx4 c0 = (floatx4)(bsc), c1 = (floatx4)(bsc); \
    _Pragma("unroll") \
    for (int ks = 0; ks < 4; ks++) { \
      c0 = __builtin_amdgcn_mfma_f32_16x16x32_bf16(areg[0][ks], bb[ks], c0, 0, 0, 0); \
      c1 = __builtin_amdgcn_mfma_f32_16x16x32_bf16(areg[1][ks], bb[ks], c1, 0, 0, 0); }

  if (wv < 3) {
    // ss/vs class: u in [0,192); wave ranges [0,63),[63,126),[126,192)
    const int ng = (wv == 2) ? 22 : 21;
    const int base_ai = wv * 21;
    const int u0 = base_ai * 3;
    float accS[3][2][4];
#pragma unroll
    for (int c = 0; c < 3; c++)
#pragma unroll
      for (int mt = 0; mt < 2; mt++)
#pragma unroll
        for (int r = 0; r < 4; r++) accS[c][mt][r] = 0.f;

    short8 b0[4], b1[4], b2[4];
    float bb0, bb1, bb2;
    LOADB(b0, bb0, u0); LOADB(b1, bb1, u0 + 1);
    for (int g = 0; g < ng; g++) {
      const int ai = base_ai + g;
      const int u = u0 + 3 * g;
      float av[2][4];
#pragma unroll
      for (int mt = 0; mt < 2; mt++)
#pragma unroll
        for (int r = 0; r < 4; r++)
          av[mt][r] = bf2f(a_lds[(mt * 16 + q * 4 + r) * 161 + ai]);

#define COMP_SS(bb, bsc, cidx) { \
      MFMA8(bb, bsc, c0, c1); \
      _Pragma("unroll") \
      for (int r = 0; r < 4; r++) { \
        accS[cidx][0][r] += av[0][r] * dlrelu(c0[r]); \
        accS[cidx][1][r] += av[1][r] * dlrelu(c1[r]); } }

      LOADB(b2, bb2, u + 2); COMP_SS(b0, bb0, 0);
      LOADB(b0, bb0, u + 3); COMP_SS(b1, bb1, 1);
      LOADB(b1, bb1, u + 4); COMP_SS(b2, bb2, 2);
    }
    // phase 4 (ss): direct global scatter, lane owns (e, c*16+cl)
#pragma unroll
    for (int mt = 0; mt < 2; mt++)
#pragma unroll
      for (int r = 0; r < 4; r++) {
        int e = mt * 16 + q * 4 + r;
        float* mrow = msg + (size_t)dst_lds[e] * CH;
#pragma unroll
        for (int c = 0; c < 3; c++)
          atomicAdd(mrow + c * 16 + cl, ALPHA * accS[c][mt][r]);
      }
  } else {
    // wave 3: sv u[192,240) + vv u[240,256)
    float accT[2][4], accV[2][4][3];
#pragma unroll
    for (int mt = 0; mt < 2; mt++)
#pragma unroll
      for (int r = 0; r < 4; r++) {
        accT[mt][r] = 0.f;
        accV[mt][r][0] = 0.f; accV[mt][r][1] = 0.f; accV[mt][r][2] = 0.f;
      }
    short8 b0[4], b1[4];
    float bb0, bb1;

#define COMP_SV(bb, bsc, uu) { \
    const int ai = (uu) - 128; \
    MFMA8(bb, bsc, c0, c1); \
    _Pragma("unroll") \
    for (int r = 0; r < 4; r++) { \
      accT[0][r] += bf2f(a_lds[(q * 4 + r) * 161 + ai]) * dlrelu(c0[r]); \
      accT[1][r] += bf2f(a_lds[(16 + q * 4 + r) * 161 + ai]) * dlrelu(c1[r]); } }

#define COMP_VV(bb, bsc, uu) { \
    const int ab = 3 * (uu) - 608; \
    MFMA8(bb, bsc, c0, c1); \
    _Pragma("unroll") \
    for (int r = 0; r < 4; r++) { \
      float w0 = dlrelu(c0[r]), w1v = dlrelu(c1[r]); \
      int ba0 = (q * 4 + r) * 161 + ab, ba1 = (16 + q * 4 + r) * 161 + ab; \
      accV[0][r][0] += bf2f(a_lds[ba0 + 0]) * w0; \
      accV[0][r][1] += bf2f(a_lds[ba0 + 1]) * w0; \
      accV[0][r][2] += bf2f(a_lds[ba0 + 2]) * w0; \
      accV[1][r][0] += bf2f(a_lds[ba1 + 0]) * w1v; \
      accV[1][r][1] += bf2f(a_lds[ba1 + 1]) * w1v; \
      accV[1][r][2] += bf2f(a_lds[ba1 + 2]) * w1v; } }

    LOADB(b0, bb0, 192);
    for (int i = 0; i < 48; i += 2) {
      const int u = 192 + i;
      LOADB(b1, bb1, u + 1); COMP_SV(b0, bb0, u);
      LOADB(b0, bb0, u + 2); COMP_SV(b1, bb1, u + 1);
    }
    for (int i = 0; i < 16; i += 2) {
      const int u = 240 + i;
      LOADB(b1, bb1, u + 1); COMP_VV(b0, bb0, u);
      LOADB(b0, bb0, u + 2); COMP_VV(b1, bb1, u + 1);
    }
    // phase 4 (sv/vv): single wave -> plain LDS stores, no atomics
#pragma unroll
    for (int mt = 0; mt < 2; mt++)
#pragma unroll
      for (int r = 0; r < 4; r++) {
        int e = mt * 16 + q * 4 + r;
        tmp_l[e * 17 + cl] = accT[mt][r];
#pragma unroll
        for (int m = 0; m < 3; m++)
          vv_l[e * 49 + 3 * cl + m] = accV[mt][r][m];
      }
  }
  __syncthreads();

  // ---- phase 5: v-channels only (s already scattered)
  for (int idx = tid; idx < EB * 48; idx += 256) {
    int e = idx / 48, t2 = idx - e * 48;
    int k = t2 / 3, m = t2 - k * 3;
    float val = ALPHA * (tmp_l[e * 17 + k] * sv_lds[e][m] +
                         ss_lds[e] * vv_l[e * 49 + 3 * k + m]);
    atomicAdd(msg + (size_t)dst_lds[e] * CH + 48 + t2, val);
  }
}

// ---------------------------------------------------------------------------
// K23: BN stats + device-barrier + normalize, single kernel (512 blocks).
__global__ __launch_bounds__(256) void k23_fused(const float* na, const float* bnw,
                                                 const float* bnb, float* ws,
                                                 float* out, int ok1) {
  __shared__ float part[112];
  __shared__ float mean_s[48], scale_s[48], bias_s[48], scale_v[16];
  float* msg = ws + OFF_MSG;
  float* st = ws + OFF_ST;
  const int tid = threadIdx.x;
  const int stride = gridDim.x * 256;

  if (ok1) {
    for (int i = tid; i < 112; i += 256) part[i] = 0.f;
    __syncthreads();
    for (int idx = blockIdx.x * 256 + tid; idx < NNODES * CH; idx += stride) {
      int c = idx % CH;
      float t = msg[idx] + na[idx];
      if (c < 48) { atomicAdd(&part[c], t); atomicAdd(&part[48 + c], t * t); }
      else { int k = (c - 48) / 3; atomicAdd(&part[96 + k], t * t); }
    }
    __syncthreads();
    for (int i = tid; i < 112; i += 256) atomicAdd(&st[i], part[i]);
    // device-scope barrier (monotonic ctr: replay-safe)
    __syncthreads();
    if (tid == 0) {
      __threadfence();
      int* ctr = (int*)(st + 112);
      atomicAdd(ctr, 1);
      while (__hip_atomic_load(ctr, __ATOMIC_ACQUIRE, __HIP_MEMORY_SCOPE_AGENT) <
             (int)gridDim.x) {}
    }
    __syncthreads();
  }

  if (tid < 48) {
    float s1 = ok1 ? fin(__hip_atomic_load(&st[tid], __ATOMIC_RELAXED,
                                           __HIP_MEMORY_SCOPE_AGENT)) : 0.f;
    float s2 = ok1 ? fin(__hip_atomic_load(&st[48 + tid], __ATOMIC_RELAXED,
                                           __HIP_MEMORY_SCOPE_AGENT)) : 0.f;
    float m = s1 * (1.f / NNODES);
    float var = fmaxf(s2 * (1.f / NNODES) - m * m, 0.f);
    mean_s[tid] = m;
    scale_s[tid] = rsqrtf(var + EPS) * bnw[tid];
    bias_s[tid] = bnb[tid];
  } else if (tid < 64) {
    int k = tid - 48;
    float s2 = ok1 ? fin(__hip_atomic_load(&st[96 + k], __ATOMIC_RELAXED,
                                           __HIP_MEMORY_SCOPE_AGENT)) : 0.f;
    scale_v[k] = rsqrtf(fmaxf(s2 * (1.f / (3.f * NNODES)), 0.f) + EPS) * bnw[48 + k];
  }
  __syncthreads();
  for (int idx = blockIdx.x * 256 + tid; idx < NNODES * CH; idx += stride) {
    int c = idx % CH;
    float t = (ok1 ? msg[idx] : 0.f) + na[idx];
    float o;
    if (c < 48) o = (t - mean_s[c]) * scale_s[c] + bias_s[c];
    else { int k = (c - 48) / 3; o = t * scale_v[k]; }
    out[idx] = fin(o);
  }
}

// ---------------------------------------------------------------------------
extern "C" void kernel_launch(void* const* d_in, const int* in_sizes, int n_in,
                              void* d_out, int out_size, void* d_ws, size_t ws_size,
                              hipStream_t stream) {
  const float* na  = (const float*)d_in[0];
  const int* eidx  = (const int*)d_in[1];
  const float* ea  = (const float*)d_in[2];
  const float* esh = (const float*)d_in[3];
  const float* w1  = (const float*)d_in[4];
  const float* b1  = (const float*)d_in[5];
  const float* w2  = (const float*)d_in[6];
  const float* b2  = (const float*)d_in[7];
  const float* bnw = (const float*)d_in[8];
  const float* bnb = (const float*)d_in[9];
  float* out = (float*)d_out;
  float* ws = (float*)d_ws;
  const int ok1 = (ws_size >= (size_t)WS_BYTES1) ? 1 : 0;
  const int ok2 = (ws_size >= (size_t)WS_BYTES2) ? 1 : 0;

  hipLaunchKernelGGL(k0_prep,   dim3(256), dim3(256), 0, stream, w1, w2, ws, ok1, ok2);
  hipLaunchKernelGGL(k1_fused,  dim3(NBLK), dim3(256), 0, stream,
                     eidx, na, ea, esh, b1, b2, ws, ok2);
  hipLaunchKernelGGL(k23_fused, dim3(512), dim3(256), 0, stream,
                     na, bnw, bnb, ws, out, ok1);
}